// Round 9
// baseline (330.748 us; speedup 1.0000x reference)
//
#include <hip/hip_runtime.h>

#define BATCH 64
#define SEQ 729
#define DIM 64
#define NT 12       // k tiles of 64
#define STRB 72     // bf16 LDS row stride (Ks/Vs/Ps)
#define MSTR 68     // mask byte-row stride
#define OSTR 68     // epilogue fp32 dword-row stride

typedef __attribute__((ext_vector_type(8))) short bf16x8;
typedef __attribute__((ext_vector_type(4))) float f32x4;
typedef __attribute__((ext_vector_type(16))) float f32x16;
// 4B-aligned vector views for the 729-strided global rows
typedef int   i32x4a __attribute__((ext_vector_type(4), aligned(4)));
typedef float f32x4a __attribute__((ext_vector_type(4), aligned(4)));

__device__ __forceinline__ unsigned short f2bf(float f) {
    unsigned int u = __float_as_uint(f);
    u += 0x7fffu + ((u >> 16) & 1u);   // round-to-nearest-even
    return (unsigned short)(u >> 16);
}

__device__ __forceinline__ unsigned long long pack4bf(float a, float b, float c, float d) {
    return (unsigned long long)f2bf(a)
         | ((unsigned long long)f2bf(b) << 16)
         | ((unsigned long long)f2bf(c) << 32)
         | ((unsigned long long)f2bf(d) << 48);
}

__device__ __forceinline__ float bf2f(unsigned int hi16) {
    return __uint_as_float(hi16 << 16);
}

// tanh(x) = 1 - 2/(exp2(2x*log2e)+1); fast_tanh(-1e9) = -1 exactly
__device__ __forceinline__ float fast_tanh(float x) {
    float e = __builtin_amdgcn_exp2f(x * 2.88539008177792681f);
    return 1.0f - 2.0f * __builtin_amdgcn_rcpf(e + 1.0f);
}

// Raw barrier WITHOUT the vmcnt(0) drain (round-5 win): only LDS fenced;
// global loads/stores stay in flight; counted vmcnt at register drains.
#define BAR() do { \
    asm volatile("s_waitcnt lgkmcnt(0)" ::: "memory"); \
    __builtin_amdgcn_s_barrier(); \
    __builtin_amdgcn_sched_barrier(0); \
} while (0)

// waves_per_eu(3,3): pin the allocator's occupancy TARGET to 3 waves/EU
// (budget ~168 VGPR). Diagnosis rounds 1-4/8: with launch_bounds(256,3)
// (a MINIMUM) the allocator targets 6/EU = 84 regs and spills beyond it.
// Runtime occupancy is LDS-bound at 3 blocks/CU = 12 waves either way.
__global__ __launch_bounds__(256)
__attribute__((amdgpu_waves_per_eu(3, 3)))
void attn_kernel(
    const float* __restrict__ Qg, const float* __restrict__ Kg,
    const float* __restrict__ Vg, const int* __restrict__ Mg,
    float* __restrict__ Og, float* __restrict__ Ag)
{
    __shared__ __align__(16) unsigned char smem[50432];
    unsigned short* Ks0 = (unsigned short*)(smem);           // [k][d] bf16 (9216)
    unsigned short* Vs0 = (unsigned short*)(smem + 9216);    // [d][k] bf16 (9216)
    unsigned short* Ks1 = (unsigned short*)(smem + 18432);   // dbuf copies
    unsigned short* Vs1 = (unsigned short*)(smem + 27648);
    unsigned short* Ps  = (unsigned short*)(smem + 36864);   // Q bf16, then P bf16 (9216)
    unsigned char*  Mb8 = smem + 46080;                      // [q][k] mask bytes (4352)
    float* Ostage = (float*)smem;   // epilogue overlay on Ks0/Vs0 (17408 <= 18432)

    const int tid = threadIdx.x;
    const int q0  = blockIdx.x * 64;
    const int b   = blockIdx.y;

    const float* Qb = Qg + (size_t)b * SEQ * DIM;
    const float* Kb = Kg + (size_t)b * SEQ * DIM;
    const float* Vb = Vg + (size_t)b * SEQ * DIM;
    const int*   Mb = Mg + (size_t)b * SEQ * SEQ;
    float* Ob = Og + (size_t)b * SEQ * DIM;
    float* Ab = Ag + (size_t)b * SEQ * SEQ;

    const int lane = tid & 63;
    const int l31  = lane & 31;
    const int lh   = lane >> 5;            // k-group half (0/1)
    const int wid  = tid >> 6;
    const int wr   = wid >> 1;             // q-half of the 64-row block (0/1)
    const int wc   = wid & 1;              // k/d-half (0/1)

    // block-cooperative staging geometry (UNCHANGED, proven): 16 consecutive
    // threads cover one row's 64 cols -> 256B contiguous float4 segments
    const int rr = tid >> 4;               // row group 0..15 (+16*i)
    const int cc = (tid & 15) * 4;         // col (floats)
    const int vd0 = (tid & 15) * 4;        // V: dims
    const int vk0 = (tid >> 4) * 4;        // V: k rows
    const int prow = (wid * 16) + (lane >> 4);  // mask staging rows
    const int pcol = (lane & 15) * 4;

    float4 kr[4], vr[4];
    i32x4a mr[4];

    auto load_k = [&](int k0n) {
        #pragma unroll
        for (int i = 0; i < 4; ++i) {
            int gk = k0n + rr + 16 * i;
            kr[i] = (gk < SEQ) ? *(const float4*)(Kb + gk * DIM + cc)
                               : float4{0, 0, 0, 0};
        }
    };
    auto load_v = [&](int k0n) {
        #pragma unroll
        for (int i = 0; i < 4; ++i) {
            int gk = k0n + vk0 + i;
            vr[i] = (gk < SEQ) ? *(const float4*)(Vb + gk * DIM + vd0)
                               : float4{0, 0, 0, 0};
        }
    };
    auto load_mask = [&](int k0n) {
        #pragma unroll
        for (int i = 0; i < 4; ++i) {
            int gq = q0 + prow + 4 * i;
            int gk = k0n + pcol;
            if (gq < SEQ && gk + 3 < SEQ) {
                mr[i] = *(const i32x4a*)(Mb + (size_t)gq * SEQ + gk);
            } else if (gq < SEQ) {
                i32x4a t;
                #pragma unroll
                for (int e = 0; e < 4; ++e)
                    t[e] = (gk + e < SEQ) ? Mb[(size_t)gq * SEQ + gk + e] : 0;
                mr[i] = t;
            } else {
                mr[i] = i32x4a{0, 0, 0, 0};
            }
        }
    };
    auto drain_mask = [&]() {   // pack 0/1 ints to bytes
        #pragma unroll
        for (int i = 0; i < 4; ++i) {
            unsigned int mb = (unsigned)(mr[i][0] & 1)
                            | ((unsigned)(mr[i][1] & 1) << 8)
                            | ((unsigned)(mr[i][2] & 1) << 16)
                            | ((unsigned)(mr[i][3] & 1) << 24);
            *(unsigned int*)&Mb8[(prow + 4 * i) * MSTR + pcol] = mb;
        }
    };
    auto drain_kv = [&](unsigned short* Kd, unsigned short* Vd) {
        #pragma unroll
        for (int i = 0; i < 4; ++i)
            *(unsigned long long*)&Kd[(rr + 16 * i) * STRB + cc] =
                pack4bf(kr[i].x, kr[i].y, kr[i].z, kr[i].w);
        #pragma unroll
        for (int j = 0; j < 4; ++j) {
            float v0 = j==0?vr[0].x:j==1?vr[0].y:j==2?vr[0].z:vr[0].w;
            float v1 = j==0?vr[1].x:j==1?vr[1].y:j==2?vr[1].z:vr[1].w;
            float v2 = j==0?vr[2].x:j==1?vr[2].y:j==2?vr[2].z:vr[2].w;
            float v3 = j==0?vr[3].x:j==1?vr[3].y:j==2?vr[3].z:vr[3].w;
            *(unsigned long long*)&Vd[(vd0 + j) * STRB + vk0] = pack4bf(v0, v1, v2, v3);
        }
    };

    // ---- prologue: issue tile-0 loads (max lead); stage Q ----
    load_k(0); load_v(0); load_mask(0);
    #pragma unroll
    for (int i = 0; i < 4; ++i) {
        int gq = q0 + rr + 16 * i;
        float4 x = (gq < SEQ) ? *(const float4*)(Qb + gq * DIM + cc)
                              : float4{0, 0, 0, 0};
        *(unsigned long long*)&Ps[(rr + 16 * i) * STRB + cc] = pack4bf(x.x, x.y, x.z, x.w);
    }
    BAR();   // Q visible

    // hoist Q fragments for 32x32x16 (A-frag: row=l31, k=16t+8*lh)
    bf16x8 aq[4];
    #pragma unroll
    for (int t = 0; t < 4; ++t)
        aq[t] = *(const bf16x8*)&Ps[(32 * wr + l31) * STRB + 16 * t + 8 * lh];

    // drain tile 0 -> buf0; issue tile-1 loads
    drain_mask();
    drain_kv(Ks0, Vs0);
    load_k(64); load_v(64); load_mask(64);
    BAR();   // buf0 + mask0 visible

    f32x16 oacc;
    #pragma unroll
    for (int r = 0; r < 16; ++r) oacc[r] = 0.0f;

    for (int t = 0; t < NT; ++t) {
        const int k0 = t * 64;
        const unsigned short* KsC = (t & 1) ? Ks1 : Ks0;
        const unsigned short* VsC = (t & 1) ? Vs1 : Vs0;
        unsigned short* KsN = (t & 1) ? Ks0 : Ks1;
        unsigned short* VsN = (t & 1) ? Vs0 : Vs1;

        // ---- QK^T: wave owns S[32q x 32k] quadrant; 4 b128 + 4 MFMA ----
        f32x16 sacc;
        #pragma unroll
        for (int r = 0; r < 16; ++r) sacc[r] = 0.0f;
        #pragma unroll
        for (int tt = 0; tt < 4; ++tt) {
            bf16x8 bk = *(const bf16x8*)&KsC[(32 * wc + l31) * STRB + 16 * tt + 8 * lh];
            sacc = __builtin_amdgcn_mfma_f32_32x32x16_bf16(aq[tt], bk, sacc, 0, 0, 0);
        }

        // ---- scale, mask, tanh, zero-diag; write P bf16 ----
        // C/D: col = l31 (k), row = (r&3)+8*(r>>2)+4*lh (q)  [m74/m101]
        #pragma unroll
        for (int r = 0; r < 16; ++r) {
            int qloc = 32 * wr + (r & 3) + 8 * (r >> 2) + 4 * lh;
            int kloc = 32 * wc + l31;
            int gq = q0 + qloc;
            int gk = k0 + kloc;
            int m = Mb8[qloc * MSTR + kloc];
            float sv = sacc[r] * 0.125f;           // 1/sqrt(64)
            float p = fast_tanh((m == 0) ? -1e9f : sv);
            if (gq == gk || gk >= SEQ) p = 0.0f;   // ignore_diag + padding
            Ps[qloc * STRB + kloc] = f2bf(p);
        }

        // ---- attention write-out (own quadrant, no barrier needed):
        //      2 b128 LDS reads; 128B-contiguous row chunks to global ----
        #pragma unroll
        for (int i = 0; i < 2; ++i) {
            int rloc = 32 * wr + (lane >> 2) + 16 * i;
            int gq   = q0 + rloc;
            int gk   = k0 + 32 * wc + 8 * (lane & 3);
            bf16x8 w = *(const bf16x8*)&Ps[rloc * STRB + 32 * wc + 8 * (lane & 3)];
            if (gq < SEQ) {
                if (gk + 7 < SEQ) {
                    f32x4a v0, v1;
                    v0[0] = bf2f((unsigned short)w[0]); v0[1] = bf2f((unsigned short)w[1]);
                    v0[2] = bf2f((unsigned short)w[2]); v0[3] = bf2f((unsigned short)w[3]);
                    v1[0] = bf2f((unsigned short)w[4]); v1[1] = bf2f((unsigned short)w[5]);
                    v1[2] = bf2f((unsigned short)w[6]); v1[3] = bf2f((unsigned short)w[7]);
                    *(f32x4a*)(Ab + (size_t)gq * SEQ + gk)     = v0;
                    *(f32x4a*)(Ab + (size_t)gq * SEQ + gk + 4) = v1;
                } else {
                    #pragma unroll
                    for (int e = 0; e < 8; ++e)
                        if (gk + e < SEQ)
                            Ab[(size_t)gq * SEQ + gk + e] = bf2f((unsigned short)w[e]);
                }
            }
        }

        BAR();   // P rows cross wave-pairs for PV; also mask-t readers done

        // ---- PV: O[32q x 32d] quadrant over FULL k; 8 b128 + 4 MFMA ----
        // A = P[q][k] rows (l31=q, k contig); B = Vs[d][k] rows (l31=d)
        #pragma unroll
        for (int tt = 0; tt < 4; ++tt) {
            bf16x8 ap = *(const bf16x8*)&Ps[(32 * wr + l31) * STRB + 16 * tt + 8 * lh];
            bf16x8 bv = *(const bf16x8*)&VsC[(32 * wc + l31) * STRB + 16 * tt + 8 * lh];
            oacc = __builtin_amdgcn_mfma_f32_32x32x16_bf16(ap, bv, oacc, 0, 0, 0);
        }

        // ---- drain tile t+1 (full compute phase of vmcnt lead); load t+2 ----
        if (t + 1 < NT) {
            drain_mask();
            drain_kv(KsN, VsN);
            if (t + 2 < NT) {
                load_k(k0 + 128); load_v(k0 + 128); load_mask(k0 + 128);
            }
            BAR();   // staging visible; current-buffer readers done
        }
    }

    // ---- O epilogue: stage oacc quadrants (overlay on dead Ks0/Vs0),
    //      BAR, then row-linear 256B float4 stores ----
    #pragma unroll
    for (int r = 0; r < 16; ++r) {
        int row = 32 * wr + (r & 3) + 8 * (r >> 2) + 4 * lh;
        Ostage[row * OSTR + 32 * wc + l31] = oacc[r];
    }
    BAR();   // quadrants cross waves for full-row readback
    #pragma unroll
    for (int i = 0; i < 4; ++i) {
        int row = 16 * wid + (lane >> 4) + 4 * i;
        int gq  = q0 + row;
        f32x4 ov = *(const f32x4*)&Ostage[row * OSTR + pcol];
        if (gq < SEQ) *(f32x4*)(Ob + (size_t)gq * DIM + pcol) = ov;  // 16B-aligned
    }
}

extern "C" void kernel_launch(void* const* d_in, const int* in_sizes, int n_in,
                              void* d_out, int out_size, void* d_ws, size_t ws_size,
                              hipStream_t stream) {
    const float* Q = (const float*)d_in[0];
    const float* K = (const float*)d_in[1];
    const float* V = (const float*)d_in[2];
    const int*   M = (const int*)d_in[3];
    float* Out  = (float*)d_out;
    float* Attn = Out + (size_t)BATCH * SEQ * DIM;   // tuple order: (out, attention)
    dim3 grid(NT, BATCH);
    attn_kernel<<<grid, 256, 0, stream>>>(Q, K, V, M, Out, Attn);
}